// Round 10
// baseline (151.066 us; speedup 1.0000x reference)
//
#include <hip/hip_runtime.h>
#include <stdint.h>

#define BB 8
#define NN 2048
#define DD 64
#define DELTA 0.1625f
#define FREQ_SCALE 0.325f

typedef __bf16 bf16x8 __attribute__((ext_vector_type(8)));
typedef float f32x4 __attribute__((ext_vector_type(4)));
typedef unsigned int u32x4 __attribute__((ext_vector_type(4)));
typedef unsigned int u32x2 __attribute__((ext_vector_type(2)));

static __device__ __forceinline__ unsigned short f2b(float x) {
    union { float f; unsigned int u; } c; c.f = x;
    unsigned int r = (c.u + 0x7FFFu + ((c.u >> 16) & 1u)) >> 16;
    return (unsigned short)r;
}

static __device__ __forceinline__ void gl_lds16(const void* g, void* l) {
    __builtin_amdgcn_global_load_lds(
        (const __attribute__((address_space(1))) void*)g,
        (__attribute__((address_space(3))) void*)l, 16, 0, 0);
}

// ---------------- prep: normalize embeddings, echo layers, e0 (f32) + e0^T (bf16)
__global__ __launch_bounds__(256) void prep_norm(
        const float* __restrict__ emb, const float* __restrict__ freq,
        float* __restrict__ e0, unsigned short* __restrict__ eT0,
        int* __restrict__ echo, int* __restrict__ counts) {
    __shared__ unsigned short tile[64][72];
    int t = threadIdx.x;
    int tok0 = blockIdx.x * 64;
    int lt = t >> 2;
    int tt = tok0 + lt;
    int dd = (t & 3) * 16;

    if (blockIdx.x == 0 && t < 40) counts[t] = 0;   // [5][8] zero-init

    const float* src = emb + (size_t)tt * DD + dd;
    f32x4 v[4];
    float ss = 0.f;
    #pragma unroll
    for (int q = 0; q < 4; q++) {
        v[q] = *(const f32x4*)(src + q * 4);
        ss += v[q].x*v[q].x + v[q].y*v[q].y + v[q].z*v[q].z + v[q].w*v[q].w;
    }
    ss += __shfl_xor(ss, 1);
    ss += __shfl_xor(ss, 2);
    float scale = 1.f / fmaxf(sqrtf(ss), 1e-12f);
    float* dst = e0 + (size_t)tt * DD + dd;
    #pragma unroll
    for (int q = 0; q < 4; q++) {
        f32x4 o = v[q] * scale;
        *(f32x4*)(dst + q * 4) = o;
        tile[lt][dd + q*4 + 0] = f2b(o.x);
        tile[lt][dd + q*4 + 1] = f2b(o.y);
        tile[lt][dd + q*4 + 2] = f2b(o.z);
        tile[lt][dd + q*4 + 3] = f2b(o.w);
    }
    if ((t & 3) == 0) {
        int el = 1 + (int)floorf(freq[tt] * FREQ_SCALE);
        el = el < 1 ? 1 : (el > 5 ? 5 : el);
        echo[tt] = el;
    }
    __syncthreads();
    int b  = tok0 / NN;
    int tb = tok0 % NN;
    for (int idx = t; idx < 64 * 64; idx += 256) {
        int d = idx >> 6, j = idx & 63;
        eT0[((size_t)b * DD + d) * NN + tb + j] = tile[j][d];
    }
}

// ---------------- build active-token lists per (layer, batch); pad to x64
__global__ __launch_bounds__(256) void build_lists(
        const int* __restrict__ echo, int* __restrict__ ids,
        int* __restrict__ counts) {
    int b = blockIdx.x;
    int t = threadIdx.x;
    for (int n = t; n < NN; n += 256) {
        int e = echo[b * NN + n];
        ids[(size_t)b * NN + n] = n;                 // layer 0: identity
        #pragma unroll
        for (int l = 1; l < 5; l++) {
            if (l < e) {
                int p = atomicAdd(&counts[l * BB + b], 1);
                ids[((size_t)l * BB + b) * NN + p] = n;
            }
        }
    }
    if (t == 0) counts[b] = NN;                      // layer 0 count
    __syncthreads();
    #pragma unroll
    for (int l = 1; l < 5; l++) {
        int c = counts[l * BB + b];
        if (c > 0) {
            int pad = ((c + 63) / 64) * 64;
            int fill = ids[((size_t)l * BB + b) * NN];
            for (int p = c + t; p < pad; p += 256)
                ids[((size_t)l * BB + b) * NN + p] = fill;
        }
    }
}

// ---------------- cast + rowsum: one wave per rm row, pure streaming
template<bool WRB>
__global__ __launch_bounds__(256) void cast_rowsum(
        const float* __restrict__ rm, unsigned short* __restrict__ rmb,
        float* __restrict__ rowsum) {
    int gw = (int)((blockIdx.x * 256 + threadIdx.x) >> 6);   // row 0..B*N-1
    int l = threadIdx.x & 63;
    const float* src = rm + (size_t)gw * NN;
    f32x4 v[8];
    #pragma unroll
    for (int q = 0; q < 8; q++)
        v[q] = *(const f32x4*)(src + q * 256 + l * 4);
    float s = 0.f;
    #pragma unroll
    for (int q = 0; q < 8; q++)
        s += (v[q].x + v[q].y) + (v[q].z + v[q].w);
    if constexpr (WRB) {
        unsigned short* dst = rmb + (size_t)gw * NN;
        #pragma unroll
        for (int q = 0; q < 8; q++) {
            u32x2 o;
            o.x = (unsigned)f2b(v[q].x) | ((unsigned)f2b(v[q].y) << 16);
            o.y = (unsigned)f2b(v[q].z) | ((unsigned)f2b(v[q].w) << 16);
            *(u32x2*)(dst + q * 256 + l * 4) = o;
        }
    }
    #pragma unroll
    for (int m = 1; m < 64; m <<= 1) s += __shfl_xor(s, m);
    if (l == 0) rowsum[gw] = s;
}

// ---------------- layer K-split kernel, counted-vmcnt 3-buffer pipeline + row gather
// grid (32, 2, BB), block 512 = 8 waves: it = w&3 (16-row i-tile), dh = w>>2.
// Rows indirected through idsL (active tokens only); blocks beyond count exit.
__global__ __launch_bounds__(512, 2) void layer_ksplit(
        const unsigned short* __restrict__ rmb,     // [B][N][N] bf16
        const unsigned short* __restrict__ eT_src,  // [B][64][N] bf16
        float* __restrict__ partial,                // [2][B][N][64] f32
        const int* __restrict__ idsL,               // [B][N]
        const int* __restrict__ cntL) {             // [B]
    __shared__ char SA3[3][8192];   // eT tiles
    __shared__ char SB3[3][8192];   // rm tiles

    const int t = threadIdx.x;
    const int w = t >> 6, l = t & 63;
    const int lo = l & 15, hi = l >> 4;
    const int it = w & 3, dh = w >> 2;
    const int i0 = blockIdx.x * 64;
    const int ks = blockIdx.y;
    const int b  = blockIdx.z;
    const int kb0 = ks * (NN / 2);

    if (i0 >= cntL[b]) return;
    const int* idb = idsL + (size_t)b * NN;

    const char* rmB = (const char*)(rmb + (size_t)b * NN * NN + kb0);
    const char* eTB = (const char*)(eT_src + (size_t)b * DD * NN + kb0);

    // staging: wave w stages LDS rows [8w,8w+8); lane l: pos-row 8w+(l>>3), slot l&7.
    // rm source row gathered via list; eT row linear. Source col pre-swizzled by pos-row.
    const int tok_st = idb[i0 + w * 8 + (l >> 3)];
    const size_t srowR = (size_t)tok_st * (NN * 2);
    const size_t srowE = (size_t)(w * 8 + (l >> 3)) * (NN * 2);
    const int csrc = ((l & 7) ^ (l >> 3)) << 4;

    f32x4 acc0 = {}, acc1 = {};

    const int rowB  = it * 16 + lo;         // rm LDS pos-row
    const int rowA0 = dh * 32 + lo;         // eT row, dt=0
    const int rowA1 = dh * 32 + 16 + lo;    // eT row, dt=1
    const int xr = (lo & 7) << 4;           // read-side XOR key (pos-rows ≡ lo mod 8)

#define ISSUE(bi, step) do {                                       \
    const int ksb = (step) * 128;                                  \
    gl_lds16(rmB + srowR + ksb + csrc, &SB3[bi][w * 1024]);        \
    gl_lds16(eTB + srowE + ksb + csrc, &SA3[bi][w * 1024]);        \
} while (0)

#define COMP(bi) do {                                              \
    _Pragma("unroll")                                              \
    for (int kk = 0; kk < 2; kk++) {                               \
        int co = ((kk << 6) | (hi << 4)) ^ xr;                     \
        u32x4 fB  = *(const u32x4*)(&SB3[bi][rowB  * 128 + co]);   \
        u32x4 fA0 = *(const u32x4*)(&SA3[bi][rowA0 * 128 + co]);   \
        u32x4 fA1 = *(const u32x4*)(&SA3[bi][rowA1 * 128 + co]);   \
        acc0 = __builtin_amdgcn_mfma_f32_16x16x32_bf16(            \
            __builtin_bit_cast(bf16x8, fA0), __builtin_bit_cast(bf16x8, fB), acc0, 0, 0, 0); \
        acc1 = __builtin_amdgcn_mfma_f32_16x16x32_bf16(            \
            __builtin_bit_cast(bf16x8, fA1), __builtin_bit_cast(bf16x8, fB), acc1, 0, 0, 0); \
    }                                                              \
} while (0)

    ISSUE(0, 0);
    ISSUE(1, 1);
    #pragma unroll
    for (int s = 0; s < 16; s++) {
        if (s < 15) asm volatile("s_waitcnt vmcnt(2)" ::: "memory");
        else        asm volatile("s_waitcnt vmcnt(0)" ::: "memory");
        __builtin_amdgcn_s_barrier();
        __builtin_amdgcn_sched_barrier(0);
        if (s < 14) {
            const int nb = (s + 2) % 3;
            if (nb == 0)      ISSUE(0, s + 2);
            else if (nb == 1) ISSUE(1, s + 2);
            else              ISSUE(2, s + 2);
        }
        const int cb = s % 3;
        if (cb == 0)      COMP(0);
        else if (cb == 1) COMP(1);
        else              COMP(2);
    }
#undef ISSUE
#undef COMP

    // partial[ks][b][tok][d] scatter through list
    const int tok_o = idb[i0 + it * 16 + lo];
    float* pp = partial + (((size_t)ks * BB + b) * NN + tok_o) * DD
              + dh * 32 + hi * 4;
    *(f32x4*)pp = acc0;
    *(f32x4*)(pp + 16) = acc1;
}

// ---------------- reduce K-halves + shift + l2norm epilogue (+ transposed eT)
__global__ __launch_bounds__(256) void reduce_epi(
        const float* __restrict__ partial,
        const float* __restrict__ e_src,
        const float* __restrict__ rowsum_g,
        const int* __restrict__ echo,
        float* __restrict__ e_dst,
        unsigned short* __restrict__ eT_dst,
        int layer) {
    __shared__ unsigned short tile[64][72];
    int t = threadIdx.x;
    int tok0 = blockIdx.x * 64;
    int lt = t >> 2;
    int tt = tok0 + lt;
    int dd = (t & 3) * 16;

    const int active = (layer < echo[tt]) ? 1 : 0;
    const float* p0 = partial + (size_t)tt * DD + dd;
    const float* p1 = partial + ((size_t)BB * NN + tt) * DD + dd;
    const float* es = e_src + (size_t)tt * DD + dd;
    float rs = rowsum_g[tt];
    float coef = active ? DELTA : 0.f;

    f32x4 u[4];
    float ss = 0.f;
    #pragma unroll
    for (int q = 0; q < 4; q++) {
        f32x4 e = *(const f32x4*)(es + q * 4);
        f32x4 uu;
        if (active) {
            f32x4 a = *(const f32x4*)(p0 + q * 4) + *(const f32x4*)(p1 + q * 4);
            uu = e + coef * (e * rs - a);
        } else {
            uu = e;
        }
        u[q] = uu;
        ss += uu.x*uu.x + uu.y*uu.y + uu.z*uu.z + uu.w*uu.w;
    }
    ss += __shfl_xor(ss, 1);
    ss += __shfl_xor(ss, 2);
    float scale = 1.f / fmaxf(sqrtf(ss), 1e-12f);
    float* dst = e_dst + (size_t)tt * DD + dd;
    #pragma unroll
    for (int q = 0; q < 4; q++) {
        f32x4 o = u[q] * scale;
        *(f32x4*)(dst + q * 4) = o;
        tile[lt][dd + q*4 + 0] = f2b(o.x);
        tile[lt][dd + q*4 + 1] = f2b(o.y);
        tile[lt][dd + q*4 + 2] = f2b(o.z);
        tile[lt][dd + q*4 + 3] = f2b(o.w);
    }
    __syncthreads();
    int b  = tok0 / NN;
    int tb = tok0 % NN;
    for (int idx = t; idx < 64 * 64; idx += 256) {
        int d = idx >> 6, j = idx & 63;
        eT_dst[((size_t)b * DD + d) * NN + tb + j] = tile[j][d];
    }
}

// ---------------- fallback single-kernel layer (no partial buffer in ws)
__global__ __launch_bounds__(256, 2) void layer_mfma(
        const unsigned short* __restrict__ rmb,
        const unsigned short* __restrict__ eT_src,
        const float* __restrict__ e_src,
        const float* __restrict__ rowsum_g,
        const int* __restrict__ echo,
        float* __restrict__ e_dst,
        unsigned short* __restrict__ eT_dst,
        int layer) {
    __shared__ u32x4 SA[2][64 * 16];
    __shared__ u32x4 SB[2][32 * 16];
    __shared__ float redSS[2][2][16];

    const int t = threadIdx.x;
    const int w = t >> 6, l = t & 63;
    const int lo = l & 15, hi = l >> 4;
    const int wi = w >> 1, dh = w & 1;
    const int b = blockIdx.y;
    const int i0 = blockIdx.x * 32;

    const int sr  = l >> 4;
    const int scb = (l & 15) << 4;

    const char* rm_bytes = (const char*)(rmb + ((size_t)b * NN + i0) * NN);
    const char* eT_bytes = (const char*)(eT_src + (size_t)b * DD * NN);

    f32x4 acc0 = {}, acc1 = {};

    #define STAGE(buf, step) do {                                              \
        const int ksb = (step) * 256;                                          \
        {   int r0 = w * 8;                                                    \
            int lr = r0 + sr;                                                  \
            gl_lds16(rm_bytes + (size_t)lr * (NN*2) + ksb + (scb ^ ((lr&7)<<4)),\
                     (char*)&SB[buf][0] + r0 * 256);                           \
            r0 += 4; lr = r0 + sr;                                             \
            gl_lds16(rm_bytes + (size_t)lr * (NN*2) + ksb + (scb ^ ((lr&7)<<4)),\
                     (char*)&SB[buf][0] + r0 * 256); }                         \
        _Pragma("unroll")                                                      \
        for (int q = 0; q < 4; q++) {                                          \
            int r0 = w * 16 + q * 4;                                           \
            int lr = r0 + sr;                                                  \
            gl_lds16(eT_bytes + (size_t)lr * (NN*2) + ksb + (scb ^ ((lr&7)<<4)),\
                     (char*)&SA[buf][0] + r0 * 256); }                         \
    } while (0)

    const int rowB = wi * 16 + lo;
    const int rowA0 = dh * 32 + lo;
    const int rowA1 = dh * 32 + 16 + lo;
    const int xr = (lo & 7) << 4;

    #define COMPUTE(buf) do {                                                  \
        const char* Ab = (const char*)&SA[buf][0];                             \
        const char* Bb = (const char*)&SB[buf][0];                             \
        _Pragma("unroll")                                                      \
        for (int kk = 0; kk < 4; kk++) {                                       \
            int co = ((kk << 6) | (hi << 4)) ^ xr;                             \
            u32x4 fB  = *(const u32x4*)(Bb + rowB  * 256 + co);                \
            u32x4 fA0 = *(const u32x4*)(Ab + rowA0 * 256 + co);                \
            u32x4 fA1 = *(const u32x4*)(Ab + rowA1 * 256 + co);                \
            acc0 = __builtin_amdgcn_mfma_f32_16x16x32_bf16(                    \
                __builtin_bit_cast(bf16x8, fA0), __builtin_bit_cast(bf16x8, fB), acc0, 0, 0, 0); \
            acc1 = __builtin_amdgcn_mfma_f32_16x16x32_bf16(                    \
                __builtin_bit_cast(bf16x8, fA1), __builtin_bit_cast(bf16x8, fB), acc1, 0, 0, 0); \
        }                                                                      \
    } while (0)

    STAGE(0, 0);
    __syncthreads();
    #pragma unroll
    for (int step = 0; step < 16; step++) {
        const int cur = step & 1;
        if (step < 15) STAGE(cur ^ 1, step + 1);
        COMPUTE(cur);
        __syncthreads();
    }
    #undef STAGE
    #undef COMPUTE

    const size_t gi = (size_t)b * NN + i0 + wi * 16 + lo;
    const float rs = rowsum_g[gi];
    const float coef = (layer < echo[gi]) ? DELTA : 0.f;
    const size_t eb = gi * DD + dh * 32 + hi * 4;
    f32x4 e0 = *(const f32x4*)(e_src + eb);
    f32x4 e1 = *(const f32x4*)(e_src + eb + 16);
    f32x4 u0 = e0 + coef * (e0 * rs - acc0);
    f32x4 u1 = e1 + coef * (e1 * rs - acc1);
    float ss = u0.x*u0.x + u0.y*u0.y + u0.z*u0.z + u0.w*u0.w
             + u1.x*u1.x + u1.y*u1.y + u1.z*u1.z + u1.w*u1.w;
    ss += __shfl_xor(ss, 16);
    ss += __shfl_xor(ss, 32);
    if (hi == 0) redSS[wi][dh][lo] = ss;
    __syncthreads();
    float sst = redSS[wi][0][lo] + redSS[wi][1][lo];
    float scale = 1.f / fmaxf(sqrtf(sst), 1e-12f);
    u0 *= scale;
    u1 *= scale;
    *(f32x4*)(e_dst + eb) = u0;
    *(f32x4*)(e_dst + eb + 16) = u1;
    unsigned short* ep = eT_dst + (size_t)b * DD * NN;
    const int i = i0 + wi * 16 + lo;
    const int d0 = dh * 32 + hi * 4;
    ep[(size_t)(d0 + 0)  * NN + i] = f2b(u0.x);
    ep[(size_t)(d0 + 1)  * NN + i] = f2b(u0.y);
    ep[(size_t)(d0 + 2)  * NN + i] = f2b(u0.z);
    ep[(size_t)(d0 + 3)  * NN + i] = f2b(u0.w);
    ep[(size_t)(d0 + 16) * NN + i] = f2b(u1.x);
    ep[(size_t)(d0 + 17) * NN + i] = f2b(u1.y);
    ep[(size_t)(d0 + 18) * NN + i] = f2b(u1.z);
    ep[(size_t)(d0 + 19) * NN + i] = f2b(u1.w);
}

// ---------------- deep fallback (no bf16 cache fits): direct fp32 reads
__global__ __launch_bounds__(512, 4) void layer_step_fb(
        const float* __restrict__ rm_,
        const unsigned short* __restrict__ eT_src,
        const float* __restrict__ e_src,
        const float* __restrict__ rowsum_g,
        const int* __restrict__ echo,
        float* __restrict__ e_dst,
        unsigned short* __restrict__ eT_dst,
        int layer) {
    __shared__ float redAcc[3][2][64][20];

    int t = threadIdx.x;
    int w = t >> 6, l = t & 63;
    int b = blockIdx.y;
    int i0 = blockIdx.x * 32;
    int wi = w & 1;
    int kq = w >> 1;
    int lane_lo = l & 15, lane_hi = l >> 4;
    int i = i0 + wi * 16 + lane_lo;
    size_t gi = (size_t)b * NN + i;
    int kbase = kq * (NN / 4) + 8 * lane_hi;

    int echo_pre = echo[gi];
    float rs = rowsum_g[gi];

    const unsigned short* eT_b = eT_src + (size_t)b * DD * NN;
    const unsigned short* ea0 = eT_b + (size_t)(lane_lo)      * NN + kbase;
    const unsigned short* ea1 = eT_b + (size_t)(16 + lane_lo) * NN + kbase;
    const unsigned short* ea2 = eT_b + (size_t)(32 + lane_lo) * NN + kbase;
    const unsigned short* ea3 = eT_b + (size_t)(48 + lane_lo) * NN + kbase;

    f32x4 acc[4] = {};
    const float* rmp32 = rm_ + gi * NN + kbase;

    #pragma unroll
    for (int j = 0; j < 16; j++) {
        const int o = 32 * j;
        f32x4 lo4 = *(const f32x4*)(rmp32 + o);
        f32x4 hi4 = *(const f32x4*)(rmp32 + o + 4);
        u32x4 ob;
        ob.x = (unsigned)f2b(lo4.x) | ((unsigned)f2b(lo4.y) << 16);
        ob.y = (unsigned)f2b(lo4.z) | ((unsigned)f2b(lo4.w) << 16);
        ob.z = (unsigned)f2b(hi4.x) | ((unsigned)f2b(hi4.y) << 16);
        ob.w = (unsigned)f2b(hi4.z) | ((unsigned)f2b(hi4.w) << 16);
        bf16x8 bfrag = __builtin_bit_cast(bf16x8, ob);
        acc[0] = __builtin_amdgcn_mfma_f32_16x16x32_bf16(
            __builtin_bit_cast(bf16x8, *(const u32x4*)(ea0 + o)), bfrag, acc[0], 0, 0, 0);
        acc[1] = __builtin_amdgcn_mfma_f32_16x16x32_bf16(
            __builtin_bit_cast(bf16x8, *(const u32x4*)(ea1 + o)), bfrag, acc[1], 0, 0, 0);
        acc[2] = __builtin_amdgcn_mfma_f32_16x16x32_bf16(
            __builtin_bit_cast(bf16x8, *(const u32x4*)(ea2 + o)), bfrag, acc[2], 0, 0, 0);
        acc[3] = __builtin_amdgcn_mfma_f32_16x16x32_bf16(
            __builtin_bit_cast(bf16x8, *(const u32x4*)(ea3 + o)), bfrag, acc[3], 0, 0, 0);
    }

    if (kq > 0) {
        #pragma unroll
        for (int f = 0; f < 4; f++)
            *(f32x4*)(&redAcc[kq - 1][wi][l][4 * f]) = acc[f];
    }
    __syncthreads();
    if (kq == 0) {
        #pragma unroll
        for (int f = 0; f < 4; f++) {
            acc[f] += *(const f32x4*)(&redAcc[0][wi][l][4 * f]);
            acc[f] += *(const f32x4*)(&redAcc[1][wi][l][4 * f]);
            acc[f] += *(const f32x4*)(&redAcc[2][wi][l][4 * f]);
        }
        float coef = DELTA * ((layer < echo_pre) ? 1.f : 0.f);
        size_t ebase = gi * DD;
        f32x4 upd[4];
        float ss = 0.f;
        #pragma unroll
        for (int f = 0; f < 4; f++) {
            f32x4 e = *(const f32x4*)(e_src + ebase + 16 * f + 4 * lane_hi);
            f32x4 u = e + coef * (e * rs - acc[f]);
            upd[f] = u;
            ss += u.x*u.x + u.y*u.y + u.z*u.z + u.w*u.w;
        }
        ss += __shfl_xor(ss, 16);
        ss += __shfl_xor(ss, 32);
        float scale = 1.f / fmaxf(sqrtf(ss), 1e-12f);
        unsigned short* ep = eT_dst + (size_t)b * DD * NN;
        #pragma unroll
        for (int f = 0; f < 4; f++) {
            f32x4 o = upd[f] * scale;
            *(f32x4*)(e_dst + ebase + 16 * f + 4 * lane_hi) = o;
            int dbase = 16 * f + 4 * lane_hi;
            ep[(size_t)(dbase + 0) * NN + i] = f2b(o.x);
            ep[(size_t)(dbase + 1) * NN + i] = f2b(o.y);
            ep[(size_t)(dbase + 2) * NN + i] = f2b(o.z);
            ep[(size_t)(dbase + 3) * NN + i] = f2b(o.w);
        }
    }
}

extern "C" void kernel_launch(void* const* d_in, const int* in_sizes, int n_in,
                              void* d_out, int out_size, void* d_ws, size_t ws_size,
                              hipStream_t stream) {
    const float* emb  = (const float*)d_in[0];
    const float* freq = (const float*)d_in[1];
    const float* rm   = (const float*)d_in[2];
    float* out = (float*)d_out;
    char* ws = (char*)d_ws;

    const size_t eBytes   = (size_t)BB * NN * DD * 4;     // 4 MB
    const size_t eTBytes  = (size_t)BB * DD * NN * 2;     // 2 MB
    const size_t bnBytes  = (size_t)BB * NN * 4;          // 64 KB
    const size_t rmbBytes = (size_t)BB * NN * NN * 2;     // 67 MB
    const size_t pBytes   = (size_t)2 * BB * NN * DD * 4; // 8 MB
    const size_t idBytes  = (size_t)5 * BB * NN * 4;      // 320 KB
    float* e_f32[2] = { (float*)ws, (float*)(ws + eBytes) };
    unsigned short* eT[2] = { (unsigned short*)(ws + 2*eBytes),
                              (unsigned short*)(ws + 2*eBytes + eTBytes) };
    float* rowsum = (float*)(ws + 2*eBytes + 2*eTBytes);
    int* echo = (int*)(ws + 2*eBytes + 2*eTBytes + bnBytes);
    unsigned short* rmb = (unsigned short*)(ws + 2*eBytes + 2*eTBytes + 2*bnBytes);
    size_t need_cached = 2*eBytes + 2*eTBytes + 2*bnBytes + rmbBytes;
    float* part = (float*)(ws + need_cached);
    int* ids    = (int*)(ws + need_cached + pBytes);
    int* counts = (int*)(ws + need_cached + pBytes + idBytes);
    size_t need_split = need_cached + pBytes + idBytes + 256;

    int mode = (ws_size >= need_split) ? 2 : (ws_size >= need_cached) ? 1 : 0;

    if (mode == 2) {
        prep_norm<<<dim3(BB*NN/64), dim3(256), 0, stream>>>(
            emb, freq, e_f32[0], eT[0], echo, counts);
        build_lists<<<dim3(BB), dim3(256), 0, stream>>>(echo, ids, counts);
        cast_rowsum<true><<<dim3(BB*NN/4), dim3(256), 0, stream>>>(rm, rmb, rowsum);
        for (int l = 0; l < 5; l++) {
            float* dst = (l == 4) ? out : e_f32[(l + 1) & 1];
            layer_ksplit<<<dim3(32, 2, BB), dim3(512), 0, stream>>>(
                rmb, eT[l & 1], part,
                ids + (size_t)l * BB * NN, counts + l * BB);
            reduce_epi<<<dim3(BB*NN/64), dim3(256), 0, stream>>>(
                part, e_f32[l & 1], rowsum, echo, dst, eT[(l + 1) & 1], l);
        }
    } else if (mode == 1) {
        prep_norm<<<dim3(BB*NN/64), dim3(256), 0, stream>>>(
            emb, freq, e_f32[0], eT[0], echo, (int*)rowsum /*scratch, unused*/);
        cast_rowsum<true><<<dim3(BB*NN/4), dim3(256), 0, stream>>>(rm, rmb, rowsum);
        for (int l = 0; l < 5; l++) {
            float* dst = (l == 4) ? out : e_f32[(l + 1) & 1];
            layer_mfma<<<dim3(NN/32, BB), dim3(256), 0, stream>>>(
                rmb, eT[l & 1], e_f32[l & 1], rowsum, echo,
                dst, eT[(l + 1) & 1], l);
        }
    } else {
        prep_norm<<<dim3(BB*NN/64), dim3(256), 0, stream>>>(
            emb, freq, e_f32[0], eT[0], echo, (int*)rowsum /*scratch, unused*/);
        cast_rowsum<false><<<dim3(BB*NN/4), dim3(256), 0, stream>>>(rm, nullptr, rowsum);
        for (int l = 0; l < 5; l++) {
            float* dst = (l == 4) ? out : e_f32[(l + 1) & 1];
            layer_step_fb<<<dim3(NN/32, BB), dim3(512), 0, stream>>>(
                rm, eT[l & 1], e_f32[l & 1], rowsum, echo,
                dst, eT[(l + 1) & 1], l);
        }
    }
}

// Round 11
// 126.286 us; speedup vs baseline: 1.1962x; 1.1962x over previous
//
#include <hip/hip_runtime.h>
#include <stdint.h>

#define BB 8
#define NN 2048
#define DD 64
#define DELTA 0.1625f
#define FREQ_SCALE 0.325f

typedef __bf16 bf16x8 __attribute__((ext_vector_type(8)));
typedef float f32x4 __attribute__((ext_vector_type(4)));
typedef unsigned int u32x4 __attribute__((ext_vector_type(4)));
typedef unsigned int u32x2 __attribute__((ext_vector_type(2)));

static __device__ __forceinline__ unsigned short f2b(float x) {
    union { float f; unsigned int u; } c; c.f = x;
    unsigned int r = (c.u + 0x7FFFu + ((c.u >> 16) & 1u)) >> 16;
    return (unsigned short)r;
}

static __device__ __forceinline__ void gl_lds16(const void* g, void* l) {
    __builtin_amdgcn_global_load_lds(
        (const __attribute__((address_space(1))) void*)g,
        (__attribute__((address_space(3))) void*)l, 16, 0, 0);
}

// ---------------- prep: normalize embeddings, echo layers, e0 (f32) + e0^T (bf16)
__global__ __launch_bounds__(256) void prep_norm(
        const float* __restrict__ emb, const float* __restrict__ freq,
        float* __restrict__ e0, unsigned short* __restrict__ eT0,
        int* __restrict__ echo) {
    __shared__ unsigned short tile[64][72];
    int t = threadIdx.x;
    int tok0 = blockIdx.x * 64;
    int lt = t >> 2;
    int tt = tok0 + lt;
    int dd = (t & 3) * 16;

    const float* src = emb + (size_t)tt * DD + dd;
    f32x4 v[4];
    float ss = 0.f;
    #pragma unroll
    for (int q = 0; q < 4; q++) {
        v[q] = *(const f32x4*)(src + q * 4);
        ss += v[q].x*v[q].x + v[q].y*v[q].y + v[q].z*v[q].z + v[q].w*v[q].w;
    }
    ss += __shfl_xor(ss, 1);
    ss += __shfl_xor(ss, 2);
    float scale = 1.f / fmaxf(sqrtf(ss), 1e-12f);
    float* dst = e0 + (size_t)tt * DD + dd;
    #pragma unroll
    for (int q = 0; q < 4; q++) {
        f32x4 o = v[q] * scale;
        *(f32x4*)(dst + q * 4) = o;
        tile[lt][dd + q*4 + 0] = f2b(o.x);
        tile[lt][dd + q*4 + 1] = f2b(o.y);
        tile[lt][dd + q*4 + 2] = f2b(o.z);
        tile[lt][dd + q*4 + 3] = f2b(o.w);
    }
    if ((t & 3) == 0) {
        int el = 1 + (int)floorf(freq[tt] * FREQ_SCALE);
        el = el < 1 ? 1 : (el > 5 ? 5 : el);
        echo[tt] = el;
    }
    __syncthreads();
    int b  = tok0 / NN;
    int tb = tok0 % NN;
    for (int idx = t; idx < 64 * 64; idx += 256) {
        int d = idx >> 6, j = idx & 63;
        eT0[((size_t)b * DD + d) * NN + tb + j] = tile[j][d];
    }
}

// ---------------- cast + rowsum: one wave per rm row, pure streaming
template<bool WRB>
__global__ __launch_bounds__(256) void cast_rowsum(
        const float* __restrict__ rm, unsigned short* __restrict__ rmb,
        float* __restrict__ rowsum) {
    int gw = (int)((blockIdx.x * 256 + threadIdx.x) >> 6);   // row 0..B*N-1
    int l = threadIdx.x & 63;
    const float* src = rm + (size_t)gw * NN;
    f32x4 v[8];
    #pragma unroll
    for (int q = 0; q < 8; q++)
        v[q] = *(const f32x4*)(src + q * 256 + l * 4);
    float s = 0.f;
    #pragma unroll
    for (int q = 0; q < 8; q++)
        s += (v[q].x + v[q].y) + (v[q].z + v[q].w);
    if constexpr (WRB) {
        unsigned short* dst = rmb + (size_t)gw * NN;
        #pragma unroll
        for (int q = 0; q < 8; q++) {
            u32x2 o;
            o.x = (unsigned)f2b(v[q].x) | ((unsigned)f2b(v[q].y) << 16);
            o.y = (unsigned)f2b(v[q].z) | ((unsigned)f2b(v[q].w) << 16);
            *(u32x2*)(dst + q * 256 + l * 4) = o;
        }
    }
    #pragma unroll
    for (int m = 1; m < 64; m <<= 1) s += __shfl_xor(s, m);
    if (l == 0) rowsum[gw] = s;
}

// ---------------- fused layer: full-K MFMA + shift + l2norm epilogue, depth-4 pipeline
// grid (NN/64, BB), block 512 = 8 waves: it = w&3 (16-row i-tile), dh = w>>2 (32-col d-half).
// BK=64: rm[64 rows][128B], eT[64 rows][128B]; 4 buffers; 32 K-steps.
// Protocol: vmcnt(4) (2/0 at drain) + raw s_barrier; ISSUE(s+3) after barrier.
__global__ __launch_bounds__(512, 1) void layer_fused(
        const unsigned short* __restrict__ rmb,     // [B][N][N] bf16
        const unsigned short* __restrict__ eT_src,  // [B][64][N] bf16
        const float* __restrict__ e_src,            // [B][N][64] f32
        const float* __restrict__ rowsum_g,
        const int* __restrict__ echo,
        float* __restrict__ e_dst,
        unsigned short* __restrict__ eT_dst,
        int layer) {
    __shared__ char SB4[4][8192];   // rm tiles
    __shared__ char SA4[4][8192];   // eT tiles
    __shared__ float redSS[4][2][16];

    const int t = threadIdx.x;
    const int w = t >> 6, l = t & 63;
    const int lo = l & 15, hi = l >> 4;
    const int it = w & 3, dh = w >> 2;
    const int i0 = blockIdx.x * 64;
    const int b  = blockIdx.y;

    const char* rmB = (const char*)(rmb + ((size_t)b * NN + i0) * NN);
    const char* eTB = (const char*)(eT_src + (size_t)b * DD * NN);

    // staging: wave w stages LDS rows [8w,8w+8); lane l: row 8w+(l>>3), slot l&7.
    // LDS dest linear; source col pre-swizzled so LDS[r][p] = global[r][p^(r&7)].
    const size_t srow = (size_t)(w * 8 + (l >> 3)) * (NN * 2);
    const int csrc = ((l & 7) ^ (l >> 3)) << 4;

    f32x4 acc0 = {}, acc1 = {};

    const int rowB  = it * 16 + lo;         // rm row (i)
    const int rowA0 = dh * 32 + lo;         // eT row, dt=0
    const int rowA1 = dh * 32 + 16 + lo;    // eT row, dt=1
    const int xr = (lo & 7) << 4;           // read-side XOR key (rows ≡ lo mod 8)

#define ISSUE(bi, step) do {                                       \
    const int ksb = (step) * 128;                                  \
    gl_lds16(rmB + srow + ksb + csrc, &SB4[bi][w * 1024]);         \
    gl_lds16(eTB + srow + ksb + csrc, &SA4[bi][w * 1024]);         \
} while (0)

#define COMP(bi) do {                                              \
    _Pragma("unroll")                                              \
    for (int kk = 0; kk < 2; kk++) {                               \
        int co = ((kk << 6) | (hi << 4)) ^ xr;                     \
        u32x4 fB  = *(const u32x4*)(&SB4[bi][rowB  * 128 + co]);   \
        u32x4 fA0 = *(const u32x4*)(&SA4[bi][rowA0 * 128 + co]);   \
        u32x4 fA1 = *(const u32x4*)(&SA4[bi][rowA1 * 128 + co]);   \
        acc0 = __builtin_amdgcn_mfma_f32_16x16x32_bf16(            \
            __builtin_bit_cast(bf16x8, fA0), __builtin_bit_cast(bf16x8, fB), acc0, 0, 0, 0); \
        acc1 = __builtin_amdgcn_mfma_f32_16x16x32_bf16(            \
            __builtin_bit_cast(bf16x8, fA1), __builtin_bit_cast(bf16x8, fB), acc1, 0, 0, 0); \
    }                                                              \
} while (0)

    ISSUE(0, 0);
    ISSUE(1, 1);
    ISSUE(2, 2);
    #pragma unroll
    for (int s = 0; s < 32; s++) {
        if (s < 30)      asm volatile("s_waitcnt vmcnt(4)" ::: "memory");
        else if (s == 30) asm volatile("s_waitcnt vmcnt(2)" ::: "memory");
        else             asm volatile("s_waitcnt vmcnt(0)" ::: "memory");
        __builtin_amdgcn_s_barrier();
        __builtin_amdgcn_sched_barrier(0);
        if (s < 29) {
            const int nb = (s + 3) & 3;
            if (nb == 0)      ISSUE(0, s + 3);
            else if (nb == 1) ISSUE(1, s + 3);
            else if (nb == 2) ISSUE(2, s + 3);
            else              ISSUE(3, s + 3);
        }
        const int cb = s & 3;
        if (cb == 0)      COMP(0);
        else if (cb == 1) COMP(1);
        else if (cb == 2) COMP(2);
        else              COMP(3);
    }
#undef ISSUE
#undef COMP

    // epilogue: i = i0 + it*16 + lo ; d = dh*32 + dt*16 + hi*4 + r
    const size_t gi = (size_t)b * NN + i0 + it * 16 + lo;
    const float rs = rowsum_g[gi];
    const float coef = (layer < echo[gi]) ? DELTA : 0.f;
    const size_t eb = gi * DD + dh * 32 + hi * 4;
    f32x4 e0 = *(const f32x4*)(e_src + eb);
    f32x4 e1 = *(const f32x4*)(e_src + eb + 16);
    f32x4 u0 = e0 + coef * (e0 * rs - acc0);
    f32x4 u1 = e1 + coef * (e1 * rs - acc1);
    float ss = u0.x*u0.x + u0.y*u0.y + u0.z*u0.z + u0.w*u0.w
             + u1.x*u1.x + u1.y*u1.y + u1.z*u1.z + u1.w*u1.w;
    ss += __shfl_xor(ss, 16);
    ss += __shfl_xor(ss, 32);
    if (hi == 0) redSS[it][dh][lo] = ss;
    __syncthreads();
    float sst = redSS[it][0][lo] + redSS[it][1][lo];
    float scale = 1.f / fmaxf(sqrtf(sst), 1e-12f);
    u0 *= scale;
    u1 *= scale;
    *(f32x4*)(e_dst + eb) = u0;
    *(f32x4*)(e_dst + eb + 16) = u1;
    unsigned short* ep = eT_dst + (size_t)b * DD * NN;
    const int i = i0 + it * 16 + lo;
    const int d0 = dh * 32 + hi * 4;
    ep[(size_t)(d0 + 0)  * NN + i] = f2b(u0.x);
    ep[(size_t)(d0 + 1)  * NN + i] = f2b(u0.y);
    ep[(size_t)(d0 + 2)  * NN + i] = f2b(u0.z);
    ep[(size_t)(d0 + 3)  * NN + i] = f2b(u0.w);
    ep[(size_t)(d0 + 16) * NN + i] = f2b(u1.x);
    ep[(size_t)(d0 + 17) * NN + i] = f2b(u1.y);
    ep[(size_t)(d0 + 18) * NN + i] = f2b(u1.z);
    ep[(size_t)(d0 + 19) * NN + i] = f2b(u1.w);
}

// ---------------- deep fallback (no bf16 cache fits): direct fp32 reads
__global__ __launch_bounds__(512, 4) void layer_step_fb(
        const float* __restrict__ rm_,
        const unsigned short* __restrict__ eT_src,
        const float* __restrict__ e_src,
        const float* __restrict__ rowsum_g,
        const int* __restrict__ echo,
        float* __restrict__ e_dst,
        unsigned short* __restrict__ eT_dst,
        int layer) {
    __shared__ float redAcc[3][2][64][20];

    int t = threadIdx.x;
    int w = t >> 6, l = t & 63;
    int b = blockIdx.y;
    int i0 = blockIdx.x * 32;
    int wi = w & 1;
    int kq = w >> 1;
    int lane_lo = l & 15, lane_hi = l >> 4;
    int i = i0 + wi * 16 + lane_lo;
    size_t gi = (size_t)b * NN + i;
    int kbase = kq * (NN / 4) + 8 * lane_hi;

    int echo_pre = echo[gi];
    float rs = rowsum_g[gi];

    const unsigned short* eT_b = eT_src + (size_t)b * DD * NN;
    const unsigned short* ea0 = eT_b + (size_t)(lane_lo)      * NN + kbase;
    const unsigned short* ea1 = eT_b + (size_t)(16 + lane_lo) * NN + kbase;
    const unsigned short* ea2 = eT_b + (size_t)(32 + lane_lo) * NN + kbase;
    const unsigned short* ea3 = eT_b + (size_t)(48 + lane_lo) * NN + kbase;

    f32x4 acc[4] = {};
    const float* rmp32 = rm_ + gi * NN + kbase;

    #pragma unroll
    for (int j = 0; j < 16; j++) {
        const int o = 32 * j;
        f32x4 lo4 = *(const f32x4*)(rmp32 + o);
        f32x4 hi4 = *(const f32x4*)(rmp32 + o + 4);
        u32x4 ob;
        ob.x = (unsigned)f2b(lo4.x) | ((unsigned)f2b(lo4.y) << 16);
        ob.y = (unsigned)f2b(lo4.z) | ((unsigned)f2b(lo4.w) << 16);
        ob.z = (unsigned)f2b(hi4.x) | ((unsigned)f2b(hi4.y) << 16);
        ob.w = (unsigned)f2b(hi4.z) | ((unsigned)f2b(hi4.w) << 16);
        bf16x8 bfrag = __builtin_bit_cast(bf16x8, ob);
        acc[0] = __builtin_amdgcn_mfma_f32_16x16x32_bf16(
            __builtin_bit_cast(bf16x8, *(const u32x4*)(ea0 + o)), bfrag, acc[0], 0, 0, 0);
        acc[1] = __builtin_amdgcn_mfma_f32_16x16x32_bf16(
            __builtin_bit_cast(bf16x8, *(const u32x4*)(ea1 + o)), bfrag, acc[1], 0, 0, 0);
        acc[2] = __builtin_amdgcn_mfma_f32_16x16x32_bf16(
            __builtin_bit_cast(bf16x8, *(const u32x4*)(ea2 + o)), bfrag, acc[2], 0, 0, 0);
        acc[3] = __builtin_amdgcn_mfma_f32_16x16x32_bf16(
            __builtin_bit_cast(bf16x8, *(const u32x4*)(ea3 + o)), bfrag, acc[3], 0, 0, 0);
    }

    if (kq > 0) {
        #pragma unroll
        for (int f = 0; f < 4; f++)
            *(f32x4*)(&redAcc[kq - 1][wi][l][4 * f]) = acc[f];
    }
    __syncthreads();
    if (kq == 0) {
        #pragma unroll
        for (int f = 0; f < 4; f++) {
            acc[f] += *(const f32x4*)(&redAcc[0][wi][l][4 * f]);
            acc[f] += *(const f32x4*)(&redAcc[1][wi][l][4 * f]);
            acc[f] += *(const f32x4*)(&redAcc[2][wi][l][4 * f]);
        }
        float coef = DELTA * ((layer < echo_pre) ? 1.f : 0.f);
        size_t ebase = gi * DD;
        f32x4 upd[4];
        float ss = 0.f;
        #pragma unroll
        for (int f = 0; f < 4; f++) {
            f32x4 e = *(const f32x4*)(e_src + ebase + 16 * f + 4 * lane_hi);
            f32x4 u = e + coef * (e * rs - acc[f]);
            upd[f] = u;
            ss += u.x*u.x + u.y*u.y + u.z*u.z + u.w*u.w;
        }
        ss += __shfl_xor(ss, 16);
        ss += __shfl_xor(ss, 32);
        float scale = 1.f / fmaxf(sqrtf(ss), 1e-12f);
        unsigned short* ep = eT_dst + (size_t)b * DD * NN;
        #pragma unroll
        for (int f = 0; f < 4; f++) {
            f32x4 o = upd[f] * scale;
            *(f32x4*)(e_dst + ebase + 16 * f + 4 * lane_hi) = o;
            int dbase = 16 * f + 4 * lane_hi;
            ep[(size_t)(dbase + 0) * NN + i] = f2b(o.x);
            ep[(size_t)(dbase + 1) * NN + i] = f2b(o.y);
            ep[(size_t)(dbase + 2) * NN + i] = f2b(o.z);
            ep[(size_t)(dbase + 3) * NN + i] = f2b(o.w);
        }
    }
}

extern "C" void kernel_launch(void* const* d_in, const int* in_sizes, int n_in,
                              void* d_out, int out_size, void* d_ws, size_t ws_size,
                              hipStream_t stream) {
    const float* emb  = (const float*)d_in[0];
    const float* freq = (const float*)d_in[1];
    const float* rm   = (const float*)d_in[2];
    float* out = (float*)d_out;
    char* ws = (char*)d_ws;

    const size_t eBytes   = (size_t)BB * NN * DD * 4;     // 4 MB
    const size_t eTBytes  = (size_t)BB * DD * NN * 2;     // 2 MB
    const size_t bnBytes  = (size_t)BB * NN * 4;          // 64 KB
    const size_t rmbBytes = (size_t)BB * NN * NN * 2;     // 67 MB
    float* e_f32[2] = { (float*)ws, (float*)(ws + eBytes) };
    unsigned short* eT[2] = { (unsigned short*)(ws + 2*eBytes),
                              (unsigned short*)(ws + 2*eBytes + eTBytes) };
    float* rowsum = (float*)(ws + 2*eBytes + 2*eTBytes);
    int* echo = (int*)(ws + 2*eBytes + 2*eTBytes + bnBytes);
    unsigned short* rmb = (unsigned short*)(ws + 2*eBytes + 2*eTBytes + 2*bnBytes);
    size_t need_cached = 2*eBytes + 2*eTBytes + 2*bnBytes + rmbBytes;

    int cached = (ws_size >= need_cached) ? 1 : 0;

    prep_norm<<<dim3(BB*NN/64), dim3(256), 0, stream>>>(emb, freq, e_f32[0], eT[0], echo);

    if (cached) {
        cast_rowsum<true><<<dim3(BB*NN/4), dim3(256), 0, stream>>>(rm, rmb, rowsum);
        for (int l = 0; l < 5; l++) {
            float* dst = (l == 4) ? out : e_f32[(l + 1) & 1];
            layer_fused<<<dim3(NN/64, BB), dim3(512), 0, stream>>>(
                rmb, eT[l & 1], e_f32[l & 1], rowsum, echo,
                dst, eT[(l + 1) & 1], l);
        }
    } else {
        cast_rowsum<false><<<dim3(BB*NN/4), dim3(256), 0, stream>>>(rm, nullptr, rowsum);
        for (int l = 0; l < 5; l++) {
            float* dst = (l == 4) ? out : e_f32[(l + 1) & 1];
            layer_step_fb<<<dim3(NN/32, BB), dim3(512), 0, stream>>>(
                rm, eT[l & 1], e_f32[l & 1], rowsum, echo,
                dst, eT[(l + 1) & 1], l);
        }
    }
}

// Round 12
// 119.308 us; speedup vs baseline: 1.2662x; 1.0585x over previous
//
#include <hip/hip_runtime.h>
#include <stdint.h>

#define BB 8
#define NN 2048
#define DD 64
#define DELTA 0.1625f
#define FREQ_SCALE 0.325f

typedef __bf16 bf16x8 __attribute__((ext_vector_type(8)));
typedef float f32x4 __attribute__((ext_vector_type(4)));
typedef unsigned int u32x4 __attribute__((ext_vector_type(4)));
typedef unsigned int u32x2 __attribute__((ext_vector_type(2)));

static __device__ __forceinline__ unsigned short f2b(float x) {
    union { float f; unsigned int u; } c; c.f = x;
    unsigned int r = (c.u + 0x7FFFu + ((c.u >> 16) & 1u)) >> 16;
    return (unsigned short)r;
}

static __device__ __forceinline__ void gl_lds16(const void* g, void* l) {
    __builtin_amdgcn_global_load_lds(
        (const __attribute__((address_space(1))) void*)g,
        (__attribute__((address_space(3))) void*)l, 16, 0, 0);
}

// ---------------- prep: normalize embeddings, echo layers, e0 (f32) + e0^T (bf16)
__global__ __launch_bounds__(256) void prep_norm(
        const float* __restrict__ emb, const float* __restrict__ freq,
        float* __restrict__ e0, unsigned short* __restrict__ eT0,
        int* __restrict__ echo) {
    __shared__ unsigned short tile[64][72];
    int t = threadIdx.x;
    int tok0 = blockIdx.x * 64;
    int lt = t >> 2;
    int tt = tok0 + lt;
    int dd = (t & 3) * 16;

    const float* src = emb + (size_t)tt * DD + dd;
    f32x4 v[4];
    float ss = 0.f;
    #pragma unroll
    for (int q = 0; q < 4; q++) {
        v[q] = *(const f32x4*)(src + q * 4);
        ss += v[q].x*v[q].x + v[q].y*v[q].y + v[q].z*v[q].z + v[q].w*v[q].w;
    }
    ss += __shfl_xor(ss, 1);
    ss += __shfl_xor(ss, 2);
    float scale = 1.f / fmaxf(sqrtf(ss), 1e-12f);
    float* dst = e0 + (size_t)tt * DD + dd;
    #pragma unroll
    for (int q = 0; q < 4; q++) {
        f32x4 o = v[q] * scale;
        *(f32x4*)(dst + q * 4) = o;
        tile[lt][dd + q*4 + 0] = f2b(o.x);
        tile[lt][dd + q*4 + 1] = f2b(o.y);
        tile[lt][dd + q*4 + 2] = f2b(o.z);
        tile[lt][dd + q*4 + 3] = f2b(o.w);
    }
    if ((t & 3) == 0) {
        int el = 1 + (int)floorf(freq[tt] * FREQ_SCALE);
        el = el < 1 ? 1 : (el > 5 ? 5 : el);
        echo[tt] = el;
    }
    __syncthreads();
    int b  = tok0 / NN;
    int tb = tok0 % NN;
    for (int idx = t; idx < 64 * 64; idx += 256) {
        int d = idx >> 6, j = idx & 63;
        eT0[((size_t)b * DD + d) * NN + tb + j] = tile[j][d];
    }
}

// ---------------- cast + rowsum: one wave per rm row, pure streaming
template<bool WRB>
__global__ __launch_bounds__(256) void cast_rowsum(
        const float* __restrict__ rm, unsigned short* __restrict__ rmb,
        float* __restrict__ rowsum) {
    int gw = (int)((blockIdx.x * 256 + threadIdx.x) >> 6);   // row 0..B*N-1
    int l = threadIdx.x & 63;
    const float* src = rm + (size_t)gw * NN;
    f32x4 v[8];
    #pragma unroll
    for (int q = 0; q < 8; q++)
        v[q] = *(const f32x4*)(src + q * 256 + l * 4);
    float s = 0.f;
    #pragma unroll
    for (int q = 0; q < 8; q++)
        s += (v[q].x + v[q].y) + (v[q].z + v[q].w);
    if constexpr (WRB) {
        unsigned short* dst = rmb + (size_t)gw * NN;
        #pragma unroll
        for (int q = 0; q < 8; q++) {
            u32x2 o;
            o.x = (unsigned)f2b(v[q].x) | ((unsigned)f2b(v[q].y) << 16);
            o.y = (unsigned)f2b(v[q].z) | ((unsigned)f2b(v[q].w) << 16);
            *(u32x2*)(dst + q * 256 + l * 4) = o;
        }
    }
    #pragma unroll
    for (int m = 1; m < 64; m <<= 1) s += __shfl_xor(s, m);
    if (l == 0) rowsum[gw] = s;
}

// ---------------- fused layer: full-K MFMA + shift + l2norm epilogue, depth-6 pipeline
// grid 256 (1D, XCD-swizzled: b = gid&7, i0 = (gid>>3)*64), block 512 = 8 waves:
// it = w&3 (16-row i-tile), dh = w>>2 (32-col d-half). BK=64; 6 buffers; 32 K-steps.
// Protocol: vmcnt(8) steady (4/2/0 drain) + raw s_barrier; ISSUE(s+5) after barrier.
__global__ __launch_bounds__(512, 1) void layer_fused(
        const unsigned short* __restrict__ rmb,     // [B][N][N] bf16
        const unsigned short* __restrict__ eT_src,  // [B][64][N] bf16
        const float* __restrict__ e_src,            // [B][N][64] f32
        const float* __restrict__ rowsum_g,
        const int* __restrict__ echo,
        float* __restrict__ e_dst,
        unsigned short* __restrict__ eT_dst,
        int layer) {
    __shared__ char SB6[6][8192];   // rm tiles
    __shared__ char SA6[6][8192];   // eT tiles
    __shared__ float redSS[4][2][16];

    const int t = threadIdx.x;
    const int w = t >> 6, l = t & 63;
    const int lo = l & 15, hi = l >> 4;
    const int it = w & 3, dh = w >> 2;
    const int gid = blockIdx.x;
    const int b  = gid & 7;              // XCD-cluster: batch b -> XCD (gid % 8)
    const int i0 = (gid >> 3) * 64;

    const char* rmB = (const char*)(rmb + ((size_t)b * NN + i0) * NN);
    const char* eTB = (const char*)(eT_src + (size_t)b * DD * NN);

    // staging: wave w stages LDS rows [8w,8w+8); lane l: row 8w+(l>>3), slot l&7.
    // LDS dest linear; source col pre-swizzled so LDS[r][p] = global[r][p^(r&7)].
    const size_t srow = (size_t)(w * 8 + (l >> 3)) * (NN * 2);
    const int csrc = ((l & 7) ^ (l >> 3)) << 4;

    f32x4 acc0 = {}, acc1 = {};

    const int rowB  = it * 16 + lo;         // rm row (i)
    const int rowA0 = dh * 32 + lo;         // eT row, dt=0
    const int rowA1 = dh * 32 + 16 + lo;    // eT row, dt=1
    const int xr = (lo & 7) << 4;           // read-side XOR key (rows ≡ lo mod 8)

#define ISSUE(bi, step) do {                                       \
    const int ksb = (step) * 128;                                  \
    gl_lds16(rmB + srow + ksb + csrc, &SB6[bi][w * 1024]);         \
    gl_lds16(eTB + srow + ksb + csrc, &SA6[bi][w * 1024]);         \
} while (0)

#define COMP(bi) do {                                              \
    __builtin_amdgcn_s_setprio(1);                                 \
    _Pragma("unroll")                                              \
    for (int kk = 0; kk < 2; kk++) {                               \
        int co = ((kk << 6) | (hi << 4)) ^ xr;                     \
        u32x4 fB  = *(const u32x4*)(&SB6[bi][rowB  * 128 + co]);   \
        u32x4 fA0 = *(const u32x4*)(&SA6[bi][rowA0 * 128 + co]);   \
        u32x4 fA1 = *(const u32x4*)(&SA6[bi][rowA1 * 128 + co]);   \
        acc0 = __builtin_amdgcn_mfma_f32_16x16x32_bf16(            \
            __builtin_bit_cast(bf16x8, fA0), __builtin_bit_cast(bf16x8, fB), acc0, 0, 0, 0); \
        acc1 = __builtin_amdgcn_mfma_f32_16x16x32_bf16(            \
            __builtin_bit_cast(bf16x8, fA1), __builtin_bit_cast(bf16x8, fB), acc1, 0, 0, 0); \
    }                                                              \
    __builtin_amdgcn_s_setprio(0);                                 \
} while (0)

    ISSUE(0, 0);
    ISSUE(1, 1);
    ISSUE(2, 2);
    ISSUE(3, 3);
    ISSUE(4, 4);
    #pragma unroll
    for (int s = 0; s < 32; s++) {
        if (s < 29)       asm volatile("s_waitcnt vmcnt(8)" ::: "memory");
        else if (s == 29) asm volatile("s_waitcnt vmcnt(4)" ::: "memory");
        else if (s == 30) asm volatile("s_waitcnt vmcnt(2)" ::: "memory");
        else              asm volatile("s_waitcnt vmcnt(0)" ::: "memory");
        __builtin_amdgcn_s_barrier();
        __builtin_amdgcn_sched_barrier(0);
        if (s < 27) {
            const int nb = (s + 5) % 6;
            if (nb == 0)      ISSUE(0, s + 5);
            else if (nb == 1) ISSUE(1, s + 5);
            else if (nb == 2) ISSUE(2, s + 5);
            else if (nb == 3) ISSUE(3, s + 5);
            else if (nb == 4) ISSUE(4, s + 5);
            else              ISSUE(5, s + 5);
        }
        const int cb = s % 6;
        if (cb == 0)      COMP(0);
        else if (cb == 1) COMP(1);
        else if (cb == 2) COMP(2);
        else if (cb == 3) COMP(3);
        else if (cb == 4) COMP(4);
        else              COMP(5);
    }
#undef ISSUE
#undef COMP

    // epilogue: i = i0 + it*16 + lo ; d = dh*32 + dt*16 + hi*4 + r
    const size_t gi = (size_t)b * NN + i0 + it * 16 + lo;
    const float rs = rowsum_g[gi];
    const float coef = (layer < echo[gi]) ? DELTA : 0.f;
    const size_t eb = gi * DD + dh * 32 + hi * 4;
    f32x4 e0 = *(const f32x4*)(e_src + eb);
    f32x4 e1 = *(const f32x4*)(e_src + eb + 16);
    f32x4 u0 = e0 + coef * (e0 * rs - acc0);
    f32x4 u1 = e1 + coef * (e1 * rs - acc1);
    float ss = u0.x*u0.x + u0.y*u0.y + u0.z*u0.z + u0.w*u0.w
             + u1.x*u1.x + u1.y*u1.y + u1.z*u1.z + u1.w*u1.w;
    ss += __shfl_xor(ss, 16);
    ss += __shfl_xor(ss, 32);
    if (hi == 0) redSS[it][dh][lo] = ss;
    __syncthreads();
    float sst = redSS[it][0][lo] + redSS[it][1][lo];
    float scale = 1.f / fmaxf(sqrtf(sst), 1e-12f);
    u0 *= scale;
    u1 *= scale;
    *(f32x4*)(e_dst + eb) = u0;
    *(f32x4*)(e_dst + eb + 16) = u1;
    unsigned short* ep = eT_dst + (size_t)b * DD * NN;
    const int i = i0 + it * 16 + lo;
    const int d0 = dh * 32 + hi * 4;
    ep[(size_t)(d0 + 0)  * NN + i] = f2b(u0.x);
    ep[(size_t)(d0 + 1)  * NN + i] = f2b(u0.y);
    ep[(size_t)(d0 + 2)  * NN + i] = f2b(u0.z);
    ep[(size_t)(d0 + 3)  * NN + i] = f2b(u0.w);
    ep[(size_t)(d0 + 16) * NN + i] = f2b(u1.x);
    ep[(size_t)(d0 + 17) * NN + i] = f2b(u1.y);
    ep[(size_t)(d0 + 18) * NN + i] = f2b(u1.z);
    ep[(size_t)(d0 + 19) * NN + i] = f2b(u1.w);
}

// ---------------- deep fallback (no bf16 cache fits): direct fp32 reads
__global__ __launch_bounds__(512, 4) void layer_step_fb(
        const float* __restrict__ rm_,
        const unsigned short* __restrict__ eT_src,
        const float* __restrict__ e_src,
        const float* __restrict__ rowsum_g,
        const int* __restrict__ echo,
        float* __restrict__ e_dst,
        unsigned short* __restrict__ eT_dst,
        int layer) {
    __shared__ float redAcc[3][2][64][20];

    int t = threadIdx.x;
    int w = t >> 6, l = t & 63;
    int b = blockIdx.y;
    int i0 = blockIdx.x * 32;
    int wi = w & 1;
    int kq = w >> 1;
    int lane_lo = l & 15, lane_hi = l >> 4;
    int i = i0 + wi * 16 + lane_lo;
    size_t gi = (size_t)b * NN + i;
    int kbase = kq * (NN / 4) + 8 * lane_hi;

    int echo_pre = echo[gi];
    float rs = rowsum_g[gi];

    const unsigned short* eT_b = eT_src + (size_t)b * DD * NN;
    const unsigned short* ea0 = eT_b + (size_t)(lane_lo)      * NN + kbase;
    const unsigned short* ea1 = eT_b + (size_t)(16 + lane_lo) * NN + kbase;
    const unsigned short* ea2 = eT_b + (size_t)(32 + lane_lo) * NN + kbase;
    const unsigned short* ea3 = eT_b + (size_t)(48 + lane_lo) * NN + kbase;

    f32x4 acc[4] = {};
    const float* rmp32 = rm_ + gi * NN + kbase;

    #pragma unroll
    for (int j = 0; j < 16; j++) {
        const int o = 32 * j;
        f32x4 lo4 = *(const f32x4*)(rmp32 + o);
        f32x4 hi4 = *(const f32x4*)(rmp32 + o + 4);
        u32x4 ob;
        ob.x = (unsigned)f2b(lo4.x) | ((unsigned)f2b(lo4.y) << 16);
        ob.y = (unsigned)f2b(lo4.z) | ((unsigned)f2b(lo4.w) << 16);
        ob.z = (unsigned)f2b(hi4.x) | ((unsigned)f2b(hi4.y) << 16);
        ob.w = (unsigned)f2b(hi4.z) | ((unsigned)f2b(hi4.w) << 16);
        bf16x8 bfrag = __builtin_bit_cast(bf16x8, ob);
        acc[0] = __builtin_amdgcn_mfma_f32_16x16x32_bf16(
            __builtin_bit_cast(bf16x8, *(const u32x4*)(ea0 + o)), bfrag, acc[0], 0, 0, 0);
        acc[1] = __builtin_amdgcn_mfma_f32_16x16x32_bf16(
            __builtin_bit_cast(bf16x8, *(const u32x4*)(ea1 + o)), bfrag, acc[1], 0, 0, 0);
        acc[2] = __builtin_amdgcn_mfma_f32_16x16x32_bf16(
            __builtin_bit_cast(bf16x8, *(const u32x4*)(ea2 + o)), bfrag, acc[2], 0, 0, 0);
        acc[3] = __builtin_amdgcn_mfma_f32_16x16x32_bf16(
            __builtin_bit_cast(bf16x8, *(const u32x4*)(ea3 + o)), bfrag, acc[3], 0, 0, 0);
    }

    if (kq > 0) {
        #pragma unroll
        for (int f = 0; f < 4; f++)
            *(f32x4*)(&redAcc[kq - 1][wi][l][4 * f]) = acc[f];
    }
    __syncthreads();
    if (kq == 0) {
        #pragma unroll
        for (int f = 0; f < 4; f++) {
            acc[f] += *(const f32x4*)(&redAcc[0][wi][l][4 * f]);
            acc[f] += *(const f32x4*)(&redAcc[1][wi][l][4 * f]);
            acc[f] += *(const f32x4*)(&redAcc[2][wi][l][4 * f]);
        }
        float coef = DELTA * ((layer < echo_pre) ? 1.f : 0.f);
        size_t ebase = gi * DD;
        f32x4 upd[4];
        float ss = 0.f;
        #pragma unroll
        for (int f = 0; f < 4; f++) {
            f32x4 e = *(const f32x4*)(e_src + ebase + 16 * f + 4 * lane_hi);
            f32x4 u = e + coef * (e * rs - acc[f]);
            upd[f] = u;
            ss += u.x*u.x + u.y*u.y + u.z*u.z + u.w*u.w;
        }
        ss += __shfl_xor(ss, 16);
        ss += __shfl_xor(ss, 32);
        float scale = 1.f / fmaxf(sqrtf(ss), 1e-12f);
        unsigned short* ep = eT_dst + (size_t)b * DD * NN;
        #pragma unroll
        for (int f = 0; f < 4; f++) {
            f32x4 o = upd[f] * scale;
            *(f32x4*)(e_dst + ebase + 16 * f + 4 * lane_hi) = o;
            int dbase = 16 * f + 4 * lane_hi;
            ep[(size_t)(dbase + 0) * NN + i] = f2b(o.x);
            ep[(size_t)(dbase + 1) * NN + i] = f2b(o.y);
            ep[(size_t)(dbase + 2) * NN + i] = f2b(o.z);
            ep[(size_t)(dbase + 3) * NN + i] = f2b(o.w);
        }
    }
}

extern "C" void kernel_launch(void* const* d_in, const int* in_sizes, int n_in,
                              void* d_out, int out_size, void* d_ws, size_t ws_size,
                              hipStream_t stream) {
    const float* emb  = (const float*)d_in[0];
    const float* freq = (const float*)d_in[1];
    const float* rm   = (const float*)d_in[2];
    float* out = (float*)d_out;
    char* ws = (char*)d_ws;

    const size_t eBytes   = (size_t)BB * NN * DD * 4;     // 4 MB
    const size_t eTBytes  = (size_t)BB * DD * NN * 2;     // 2 MB
    const size_t bnBytes  = (size_t)BB * NN * 4;          // 64 KB
    const size_t rmbBytes = (size_t)BB * NN * NN * 2;     // 67 MB
    float* e_f32[2] = { (float*)ws, (float*)(ws + eBytes) };
    unsigned short* eT[2] = { (unsigned short*)(ws + 2*eBytes),
                              (unsigned short*)(ws + 2*eBytes + eTBytes) };
    float* rowsum = (float*)(ws + 2*eBytes + 2*eTBytes);
    int* echo = (int*)(ws + 2*eBytes + 2*eTBytes + bnBytes);
    unsigned short* rmb = (unsigned short*)(ws + 2*eBytes + 2*eTBytes + 2*bnBytes);
    size_t need_cached = 2*eBytes + 2*eTBytes + 2*bnBytes + rmbBytes;

    int cached = (ws_size >= need_cached) ? 1 : 0;

    prep_norm<<<dim3(BB*NN/64), dim3(256), 0, stream>>>(emb, freq, e_f32[0], eT[0], echo);

    if (cached) {
        cast_rowsum<true><<<dim3(BB*NN/4), dim3(256), 0, stream>>>(rm, rmb, rowsum);
        for (int l = 0; l < 5; l++) {
            float* dst = (l == 4) ? out : e_f32[(l + 1) & 1];
            layer_fused<<<dim3(256), dim3(512), 0, stream>>>(
                rmb, eT[l & 1], e_f32[l & 1], rowsum, echo,
                dst, eT[(l + 1) & 1], l);
        }
    } else {
        cast_rowsum<false><<<dim3(BB*NN/4), dim3(256), 0, stream>>>(rm, nullptr, rowsum);
        for (int l = 0; l < 5; l++) {
            float* dst = (l == 4) ? out : e_f32[(l + 1) & 1];
            layer_step_fb<<<dim3(NN/32, BB), dim3(512), 0, stream>>>(
                rm, eT[l & 1], e_f32[l & 1], rowsum, echo,
                dst, eT[(l + 1) & 1], l);
        }
    }
}

// Round 13
// 106.652 us; speedup vs baseline: 1.4164x; 1.1187x over previous
//
#include <hip/hip_runtime.h>
#include <stdint.h>

#define BB 8
#define NN 2048
#define DD 64
#define DELTA 0.1625f
#define FREQ_SCALE 0.325f

typedef __bf16 bf16x8 __attribute__((ext_vector_type(8)));
typedef float f32x4 __attribute__((ext_vector_type(4)));
typedef unsigned int u32x4 __attribute__((ext_vector_type(4)));
typedef unsigned int u32x2 __attribute__((ext_vector_type(2)));

static __device__ __forceinline__ unsigned short f2b(float x) {
    union { float f; unsigned int u; } c; c.f = x;
    unsigned int r = (c.u + 0x7FFFu + ((c.u >> 16) & 1u)) >> 16;
    return (unsigned short)r;
}

static __device__ __forceinline__ void gl_lds16(const void* g, void* l) {
    __builtin_amdgcn_global_load_lds(
        (const __attribute__((address_space(1))) void*)g,
        (__attribute__((address_space(3))) void*)l, 16, 0, 0);
}

// ---------------- prep: normalize embeddings, echo layers, e0 (f32) + e0^T (bf16)
__global__ __launch_bounds__(256) void prep_norm(
        const float* __restrict__ emb, const float* __restrict__ freq,
        float* __restrict__ e0, unsigned short* __restrict__ eT0,
        int* __restrict__ echo) {
    __shared__ unsigned short tile[64][72];
    int t = threadIdx.x;
    int tok0 = blockIdx.x * 64;
    int lt = t >> 2;
    int tt = tok0 + lt;
    int dd = (t & 3) * 16;

    const float* src = emb + (size_t)tt * DD + dd;
    f32x4 v[4];
    float ss = 0.f;
    #pragma unroll
    for (int q = 0; q < 4; q++) {
        v[q] = *(const f32x4*)(src + q * 4);
        ss += v[q].x*v[q].x + v[q].y*v[q].y + v[q].z*v[q].z + v[q].w*v[q].w;
    }
    ss += __shfl_xor(ss, 1);
    ss += __shfl_xor(ss, 2);
    float scale = 1.f / fmaxf(sqrtf(ss), 1e-12f);
    float* dst = e0 + (size_t)tt * DD + dd;
    #pragma unroll
    for (int q = 0; q < 4; q++) {
        f32x4 o = v[q] * scale;
        *(f32x4*)(dst + q * 4) = o;
        tile[lt][dd + q*4 + 0] = f2b(o.x);
        tile[lt][dd + q*4 + 1] = f2b(o.y);
        tile[lt][dd + q*4 + 2] = f2b(o.z);
        tile[lt][dd + q*4 + 3] = f2b(o.w);
    }
    if ((t & 3) == 0) {
        int el = 1 + (int)floorf(freq[tt] * FREQ_SCALE);
        el = el < 1 ? 1 : (el > 5 ? 5 : el);
        echo[tt] = el;
    }
    __syncthreads();
    int b  = tok0 / NN;
    int tb = tok0 % NN;
    for (int idx = t; idx < 64 * 64; idx += 256) {
        int d = idx >> 6, j = idx & 63;
        eT0[((size_t)b * DD + d) * NN + tb + j] = tile[j][d];
    }
}

// ---------------- cast + rowsum (fallback path only)
template<bool WRB>
__global__ __launch_bounds__(256) void cast_rowsum(
        const float* __restrict__ rm, unsigned short* __restrict__ rmb,
        float* __restrict__ rowsum) {
    int gw = (int)((blockIdx.x * 256 + threadIdx.x) >> 6);
    int l = threadIdx.x & 63;
    const float* src = rm + (size_t)gw * NN;
    f32x4 v[8];
    #pragma unroll
    for (int q = 0; q < 8; q++)
        v[q] = *(const f32x4*)(src + q * 256 + l * 4);
    float s = 0.f;
    #pragma unroll
    for (int q = 0; q < 8; q++)
        s += (v[q].x + v[q].y) + (v[q].z + v[q].w);
    if constexpr (WRB) {
        unsigned short* dst = rmb + (size_t)gw * NN;
        #pragma unroll
        for (int q = 0; q < 8; q++) {
            u32x2 o;
            o.x = (unsigned)f2b(v[q].x) | ((unsigned)f2b(v[q].y) << 16);
            o.y = (unsigned)f2b(v[q].z) | ((unsigned)f2b(v[q].w) << 16);
            *(u32x2*)(dst + q * 256 + l * 4) = o;
        }
    }
    #pragma unroll
    for (int m = 1; m < 64; m <<= 1) s += __shfl_xor(s, m);
    if (l == 0) rowsum[gw] = s;
}

// ---------------- layer 0 fused: fp32 rm read + bf16 cast-out + rowsum + MFMA + epilogue
// grid 256 (XCD: b = gid&7), block 512 = 8 waves. BK=64 (f32 256B/row, bf16 128B/row).
// depth-4, lead-3; per step VMEM = 3 gl_lds + 1 store; gates 6/7/8, 9 steady, 6/3 drain.
__global__ __launch_bounds__(512, 1) void layer0_fused(
        const float* __restrict__ rm,               // [B][N][N] f32
        const unsigned short* __restrict__ eT_src,  // [B][64][N] bf16
        const float* __restrict__ e_src,            // [B][N][64] f32
        const int* __restrict__ echo,
        unsigned short* __restrict__ rmb_out,       // [B][N][N] bf16
        float* __restrict__ rowsum_out,             // [B][N]
        float* __restrict__ e_dst,
        unsigned short* __restrict__ eT_dst) {
    __shared__ char F4[4][16384];   // fp32 rm tiles [64 rows][256B], slot-swizzled
    __shared__ char C4[4][8192];    // bf16 rm tiles [64 rows][128B], slot-swizzled
    __shared__ char SA4[4][8192];   // eT tiles
    __shared__ float redSS[4][2][16];
    __shared__ float rsumL[64];

    const int t = threadIdx.x;
    const int w = t >> 6, l = t & 63;
    const int lo = l & 15, hi = l >> 4;
    const int it = w & 3, dh = w >> 2;
    const int gid = blockIdx.x;
    const int b  = gid & 7;
    const int i0 = (gid >> 3) * 64;

    const char* rmB = (const char*)(rm + ((size_t)b * NN + i0) * NN);
    const char* eTB = (const char*)(eT_src + (size_t)b * DD * NN);

    // f32 staging: lane l covers row r=(l>>4) within 4-row group, slot l&15 (16B).
    // LDS slot p of row r holds global slot p^(r&7).
    const size_t frow0 = (size_t)(w * 8 + (l >> 4)) * (NN * 4);
    const size_t frow4 = (size_t)(w * 8 + 4 + (l >> 4)) * (NN * 4);
    const int fcs0 = (((l & 15) ^ (l >> 4)) << 4);
    const int fcs4 = (((l & 15) ^ (4 + (l >> 4))) << 4);
    // eT staging (bf16 128B rows): lane l row 8w+(l>>3), slot l&7, key l>>3
    const size_t srowE = (size_t)(w * 8 + (l >> 3)) * (NN * 2);
    const int csrcE = (((l & 7) ^ (l >> 3)) << 4);

    // conversion mapping: lane l owns row rl=8w+(l>>3) (key l>>3), f32 slots 2(l&7),2(l&7)+1
    const int rl = w * 8 + (l >> 3);
    const int cs0 = ((2 * (l & 7)) ^ (l >> 3)) << 4;
    const int cs1 = ((2 * (l & 7) + 1) ^ (l >> 3)) << 4;
    const int cdst = rl * 128 + ((((l & 7) ^ (l >> 3))) << 4);
    unsigned short* rmbW = rmb_out + ((size_t)b * NN + i0 + rl) * NN + (l & 7) * 8;

    f32x4 acc0 = {}, acc1 = {};
    float rsum = 0.f;

    const int rowB  = it * 16 + lo;
    const int rowA0 = dh * 32 + lo;
    const int rowA1 = dh * 32 + 16 + lo;
    const int xr = (lo & 7) << 4;

#define ISSUE(bi, step) do {                                        \
    const int kf = (step) * 256;                                    \
    const int ke = (step) * 128;                                    \
    gl_lds16(rmB + frow0 + kf + fcs0, &F4[bi][w * 2048]);           \
    gl_lds16(rmB + frow4 + kf + fcs4, &F4[bi][w * 2048 + 1024]);    \
    gl_lds16(eTB + srowE + ke + csrcE, &SA4[bi][w * 1024]);         \
} while (0)

#define CONVERT(bi, step) do {                                      \
    f32x4 va = *(const f32x4*)(&F4[bi][rl * 256 + cs0]);            \
    f32x4 vb = *(const f32x4*)(&F4[bi][rl * 256 + cs1]);            \
    u32x4 o;                                                        \
    o.x = (unsigned)f2b(va.x) | ((unsigned)f2b(va.y) << 16);        \
    o.y = (unsigned)f2b(va.z) | ((unsigned)f2b(va.w) << 16);        \
    o.z = (unsigned)f2b(vb.x) | ((unsigned)f2b(vb.y) << 16);        \
    o.w = (unsigned)f2b(vb.z) | ((unsigned)f2b(vb.w) << 16);        \
    *(u32x4*)(&C4[bi][cdst]) = o;                                   \
    *(u32x4*)(rmbW + (step) * 64) = o;                              \
    rsum += (va.x + va.y + va.z + va.w) + (vb.x + vb.y + vb.z + vb.w); \
} while (0)

#define COMP(bi) do {                                               \
    __builtin_amdgcn_s_setprio(1);                                  \
    _Pragma("unroll")                                               \
    for (int kk = 0; kk < 2; kk++) {                                \
        int co = ((kk << 6) | (hi << 4)) ^ xr;                      \
        u32x4 fB  = *(const u32x4*)(&C4[bi][rowB  * 128 + co]);     \
        u32x4 fA0 = *(const u32x4*)(&SA4[bi][rowA0 * 128 + co]);    \
        u32x4 fA1 = *(const u32x4*)(&SA4[bi][rowA1 * 128 + co]);    \
        acc0 = __builtin_amdgcn_mfma_f32_16x16x32_bf16(             \
            __builtin_bit_cast(bf16x8, fA0), __builtin_bit_cast(bf16x8, fB), acc0, 0, 0, 0); \
        acc1 = __builtin_amdgcn_mfma_f32_16x16x32_bf16(             \
            __builtin_bit_cast(bf16x8, fA1), __builtin_bit_cast(bf16x8, fB), acc1, 0, 0, 0); \
    }                                                               \
    __builtin_amdgcn_s_setprio(0);                                  \
} while (0)

    ISSUE(0, 0);
    ISSUE(1, 1);
    ISSUE(2, 2);
    #pragma unroll
    for (int s = 0; s < 32; s++) {
        // gate: guarantee batch-s loads complete (ledger: 3 loads + 1 store/step)
        if (s == 0)       asm volatile("s_waitcnt vmcnt(6)" ::: "memory");
        else if (s == 1)  asm volatile("s_waitcnt vmcnt(7)" ::: "memory");
        else if (s == 2)  asm volatile("s_waitcnt vmcnt(8)" ::: "memory");
        else if (s < 30)  asm volatile("s_waitcnt vmcnt(9)" ::: "memory");
        else if (s == 30) asm volatile("s_waitcnt vmcnt(6)" ::: "memory");
        else              asm volatile("s_waitcnt vmcnt(3)" ::: "memory");
        __builtin_amdgcn_s_barrier();
        __builtin_amdgcn_sched_barrier(0);
        if (s < 29) {
            const int nb = (s + 3) & 3;
            if (nb == 0)      ISSUE(0, s + 3);
            else if (nb == 1) ISSUE(1, s + 3);
            else if (nb == 2) ISSUE(2, s + 3);
            else              ISSUE(3, s + 3);
        }
        const int cb = s & 3;
        if (cb == 0)      CONVERT(0, s);
        else if (cb == 1) CONVERT(1, s);
        else if (cb == 2) CONVERT(2, s);
        else              CONVERT(3, s);
        asm volatile("s_waitcnt lgkmcnt(0)" ::: "memory");
        __builtin_amdgcn_sched_barrier(0);
        __builtin_amdgcn_s_barrier();
        if (cb == 0)      COMP(0);
        else if (cb == 1) COMP(1);
        else if (cb == 2) COMP(2);
        else              COMP(3);
    }
#undef ISSUE
#undef CONVERT
#undef COMP

    // rowsum finalize: sum the 8 lanes of each row-group
    rsum += __shfl_xor(rsum, 1);
    rsum += __shfl_xor(rsum, 2);
    rsum += __shfl_xor(rsum, 4);
    if ((l & 7) == 0) {
        rsumL[rl] = rsum;
        rowsum_out[(size_t)b * NN + i0 + rl] = rsum;
    }
    __syncthreads();

    // epilogue (R12 form), rs from LDS
    const size_t gi = (size_t)b * NN + i0 + it * 16 + lo;
    const float rs = rsumL[it * 16 + lo];
    const float coef = (0 < echo[gi]) ? DELTA : 0.f;   // layer 0: always active (echo>=1)
    const size_t eb = gi * DD + dh * 32 + hi * 4;
    f32x4 e0 = *(const f32x4*)(e_src + eb);
    f32x4 e1 = *(const f32x4*)(e_src + eb + 16);
    f32x4 u0 = e0 + coef * (e0 * rs - acc0);
    f32x4 u1 = e1 + coef * (e1 * rs - acc1);
    float ss = u0.x*u0.x + u0.y*u0.y + u0.z*u0.z + u0.w*u0.w
             + u1.x*u1.x + u1.y*u1.y + u1.z*u1.z + u1.w*u1.w;
    ss += __shfl_xor(ss, 16);
    ss += __shfl_xor(ss, 32);
    if (hi == 0) redSS[it][dh][lo] = ss;
    __syncthreads();
    float sst = redSS[it][0][lo] + redSS[it][1][lo];
    float scale = 1.f / fmaxf(sqrtf(sst), 1e-12f);
    u0 *= scale;
    u1 *= scale;
    *(f32x4*)(e_dst + eb) = u0;
    *(f32x4*)(e_dst + eb + 16) = u1;
    unsigned short* ep = eT_dst + (size_t)b * DD * NN;
    const int i = i0 + it * 16 + lo;
    const int d0 = dh * 32 + hi * 4;
    ep[(size_t)(d0 + 0)  * NN + i] = f2b(u0.x);
    ep[(size_t)(d0 + 1)  * NN + i] = f2b(u0.y);
    ep[(size_t)(d0 + 2)  * NN + i] = f2b(u0.z);
    ep[(size_t)(d0 + 3)  * NN + i] = f2b(u0.w);
    ep[(size_t)(d0 + 16) * NN + i] = f2b(u1.x);
    ep[(size_t)(d0 + 17) * NN + i] = f2b(u1.y);
    ep[(size_t)(d0 + 18) * NN + i] = f2b(u1.z);
    ep[(size_t)(d0 + 19) * NN + i] = f2b(u1.w);
}

// ---------------- layers 1-4: R12 fused kernel (unchanged)
__global__ __launch_bounds__(512, 1) void layer_fused(
        const unsigned short* __restrict__ rmb,
        const unsigned short* __restrict__ eT_src,
        const float* __restrict__ e_src,
        const float* __restrict__ rowsum_g,
        const int* __restrict__ echo,
        float* __restrict__ e_dst,
        unsigned short* __restrict__ eT_dst,
        int layer) {
    __shared__ char SB6[6][8192];
    __shared__ char SA6[6][8192];
    __shared__ float redSS[4][2][16];

    const int t = threadIdx.x;
    const int w = t >> 6, l = t & 63;
    const int lo = l & 15, hi = l >> 4;
    const int it = w & 3, dh = w >> 2;
    const int gid = blockIdx.x;
    const int b  = gid & 7;
    const int i0 = (gid >> 3) * 64;

    const char* rmB = (const char*)(rmb + ((size_t)b * NN + i0) * NN);
    const char* eTB = (const char*)(eT_src + (size_t)b * DD * NN);

    const size_t srow = (size_t)(w * 8 + (l >> 3)) * (NN * 2);
    const int csrc = ((l & 7) ^ (l >> 3)) << 4;

    f32x4 acc0 = {}, acc1 = {};

    const int rowB  = it * 16 + lo;
    const int rowA0 = dh * 32 + lo;
    const int rowA1 = dh * 32 + 16 + lo;
    const int xr = (lo & 7) << 4;

#define ISSUE(bi, step) do {                                       \
    const int ksb = (step) * 128;                                  \
    gl_lds16(rmB + srow + ksb + csrc, &SB6[bi][w * 1024]);         \
    gl_lds16(eTB + srow + ksb + csrc, &SA6[bi][w * 1024]);         \
} while (0)

#define COMP(bi) do {                                              \
    __builtin_amdgcn_s_setprio(1);                                 \
    _Pragma("unroll")                                              \
    for (int kk = 0; kk < 2; kk++) {                               \
        int co = ((kk << 6) | (hi << 4)) ^ xr;                     \
        u32x4 fB  = *(const u32x4*)(&SB6[bi][rowB  * 128 + co]);   \
        u32x4 fA0 = *(const u32x4*)(&SA6[bi][rowA0 * 128 + co]);   \
        u32x4 fA1 = *(const u32x4*)(&SA6[bi][rowA1 * 128 + co]);   \
        acc0 = __builtin_amdgcn_mfma_f32_16x16x32_bf16(            \
            __builtin_bit_cast(bf16x8, fA0), __builtin_bit_cast(bf16x8, fB), acc0, 0, 0, 0); \
        acc1 = __builtin_amdgcn_mfma_f32_16x16x32_bf16(            \
            __builtin_bit_cast(bf16x8, fA1), __builtin_bit_cast(bf16x8, fB), acc1, 0, 0, 0); \
    }                                                              \
    __builtin_amdgcn_s_setprio(0);                                 \
} while (0)

    ISSUE(0, 0);
    ISSUE(1, 1);
    ISSUE(2, 2);
    ISSUE(3, 3);
    ISSUE(4, 4);
    #pragma unroll
    for (int s = 0; s < 32; s++) {
        if (s < 29)       asm volatile("s_waitcnt vmcnt(8)" ::: "memory");
        else if (s == 29) asm volatile("s_waitcnt vmcnt(4)" ::: "memory");
        else if (s == 30) asm volatile("s_waitcnt vmcnt(2)" ::: "memory");
        else              asm volatile("s_waitcnt vmcnt(0)" ::: "memory");
        __builtin_amdgcn_s_barrier();
        __builtin_amdgcn_sched_barrier(0);
        if (s < 27) {
            const int nb = (s + 5) % 6;
            if (nb == 0)      ISSUE(0, s + 5);
            else if (nb == 1) ISSUE(1, s + 5);
            else if (nb == 2) ISSUE(2, s + 5);
            else if (nb == 3) ISSUE(3, s + 5);
            else if (nb == 4) ISSUE(4, s + 5);
            else              ISSUE(5, s + 5);
        }
        const int cb = s % 6;
        if (cb == 0)      COMP(0);
        else if (cb == 1) COMP(1);
        else if (cb == 2) COMP(2);
        else if (cb == 3) COMP(3);
        else if (cb == 4) COMP(4);
        else              COMP(5);
    }
#undef ISSUE
#undef COMP

    const size_t gi = (size_t)b * NN + i0 + it * 16 + lo;
    const float rs = rowsum_g[gi];
    const float coef = (layer < echo[gi]) ? DELTA : 0.f;
    const size_t eb = gi * DD + dh * 32 + hi * 4;
    f32x4 e0 = *(const f32x4*)(e_src + eb);
    f32x4 e1 = *(const f32x4*)(e_src + eb + 16);
    f32x4 u0 = e0 + coef * (e0 * rs - acc0);
    f32x4 u1 = e1 + coef * (e1 * rs - acc1);
    float ss = u0.x*u0.x + u0.y*u0.y + u0.z*u0.z + u0.w*u0.w
             + u1.x*u1.x + u1.y*u1.y + u1.z*u1.z + u1.w*u1.w;
    ss += __shfl_xor(ss, 16);
    ss += __shfl_xor(ss, 32);
    if (hi == 0) redSS[it][dh][lo] = ss;
    __syncthreads();
    float sst = redSS[it][0][lo] + redSS[it][1][lo];
    float scale = 1.f / fmaxf(sqrtf(sst), 1e-12f);
    u0 *= scale;
    u1 *= scale;
    *(f32x4*)(e_dst + eb) = u0;
    *(f32x4*)(e_dst + eb + 16) = u1;
    unsigned short* ep = eT_dst + (size_t)b * DD * NN;
    const int i = i0 + it * 16 + lo;
    const int d0 = dh * 32 + hi * 4;
    ep[(size_t)(d0 + 0)  * NN + i] = f2b(u0.x);
    ep[(size_t)(d0 + 1)  * NN + i] = f2b(u0.y);
    ep[(size_t)(d0 + 2)  * NN + i] = f2b(u0.z);
    ep[(size_t)(d0 + 3)  * NN + i] = f2b(u0.w);
    ep[(size_t)(d0 + 16) * NN + i] = f2b(u1.x);
    ep[(size_t)(d0 + 17) * NN + i] = f2b(u1.y);
    ep[(size_t)(d0 + 18) * NN + i] = f2b(u1.z);
    ep[(size_t)(d0 + 19) * NN + i] = f2b(u1.w);
}

// ---------------- deep fallback (no bf16 cache fits): direct fp32 reads
__global__ __launch_bounds__(512, 4) void layer_step_fb(
        const float* __restrict__ rm_,
        const unsigned short* __restrict__ eT_src,
        const float* __restrict__ e_src,
        const float* __restrict__ rowsum_g,
        const int* __restrict__ echo,
        float* __restrict__ e_dst,
        unsigned short* __restrict__ eT_dst,
        int layer) {
    __shared__ float redAcc[3][2][64][20];

    int t = threadIdx.x;
    int w = t >> 6, l = t & 63;
    int b = blockIdx.y;
    int i0 = blockIdx.x * 32;
    int wi = w & 1;
    int kq = w >> 1;
    int lane_lo = l & 15, lane_hi = l >> 4;
    int i = i0 + wi * 16 + lane_lo;
    size_t gi = (size_t)b * NN + i;
    int kbase = kq * (NN / 4) + 8 * lane_hi;

    int echo_pre = echo[gi];
    float rs = rowsum_g[gi];

    const unsigned short* eT_b = eT_src + (size_t)b * DD * NN;
    const unsigned short* ea0 = eT_b + (size_t)(lane_lo)      * NN + kbase;
    const unsigned short* ea1 = eT_b + (size_t)(16 + lane_lo) * NN + kbase;
    const unsigned short* ea2 = eT_b + (size_t)(32 + lane_lo) * NN + kbase;
    const unsigned short* ea3 = eT_b + (size_t)(48 + lane_lo) * NN + kbase;

    f32x4 acc[4] = {};
    const float* rmp32 = rm_ + gi * NN + kbase;

    #pragma unroll
    for (int j = 0; j < 16; j++) {
        const int o = 32 * j;
        f32x4 lo4 = *(const f32x4*)(rmp32 + o);
        f32x4 hi4 = *(const f32x4*)(rmp32 + o + 4);
        u32x4 ob;
        ob.x = (unsigned)f2b(lo4.x) | ((unsigned)f2b(lo4.y) << 16);
        ob.y = (unsigned)f2b(lo4.z) | ((unsigned)f2b(lo4.w) << 16);
        ob.z = (unsigned)f2b(hi4.x) | ((unsigned)f2b(hi4.y) << 16);
        ob.w = (unsigned)f2b(hi4.z) | ((unsigned)f2b(hi4.w) << 16);
        bf16x8 bfrag = __builtin_bit_cast(bf16x8, ob);
        acc[0] = __builtin_amdgcn_mfma_f32_16x16x32_bf16(
            __builtin_bit_cast(bf16x8, *(const u32x4*)(ea0 + o)), bfrag, acc[0], 0, 0, 0);
        acc[1] = __builtin_amdgcn_mfma_f32_16x16x32_bf16(
            __builtin_bit_cast(bf16x8, *(const u32x4*)(ea1 + o)), bfrag, acc[1], 0, 0, 0);
        acc[2] = __builtin_amdgcn_mfma_f32_16x16x32_bf16(
            __builtin_bit_cast(bf16x8, *(const u32x4*)(ea2 + o)), bfrag, acc[2], 0, 0, 0);
        acc[3] = __builtin_amdgcn_mfma_f32_16x16x32_bf16(
            __builtin_bit_cast(bf16x8, *(const u32x4*)(ea3 + o)), bfrag, acc[3], 0, 0, 0);
    }

    if (kq > 0) {
        #pragma unroll
        for (int f = 0; f < 4; f++)
            *(f32x4*)(&redAcc[kq - 1][wi][l][4 * f]) = acc[f];
    }
    __syncthreads();
    if (kq == 0) {
        #pragma unroll
        for (int f = 0; f < 4; f++) {
            acc[f] += *(const f32x4*)(&redAcc[0][wi][l][4 * f]);
            acc[f] += *(const f32x4*)(&redAcc[1][wi][l][4 * f]);
            acc[f] += *(const f32x4*)(&redAcc[2][wi][l][4 * f]);
        }
        float coef = DELTA * ((layer < echo_pre) ? 1.f : 0.f);
        size_t ebase = gi * DD;
        f32x4 upd[4];
        float ss = 0.f;
        #pragma unroll
        for (int f = 0; f < 4; f++) {
            f32x4 e = *(const f32x4*)(e_src + ebase + 16 * f + 4 * lane_hi);
            f32x4 u = e + coef * (e * rs - acc[f]);
            upd[f] = u;
            ss += u.x*u.x + u.y*u.y + u.z*u.z + u.w*u.w;
        }
        ss += __shfl_xor(ss, 16);
        ss += __shfl_xor(ss, 32);
        float scale = 1.f / fmaxf(sqrtf(ss), 1e-12f);
        unsigned short* ep = eT_dst + (size_t)b * DD * NN;
        #pragma unroll
        for (int f = 0; f < 4; f++) {
            f32x4 o = upd[f] * scale;
            *(f32x4*)(e_dst + ebase + 16 * f + 4 * lane_hi) = o;
            int dbase = 16 * f + 4 * lane_hi;
            ep[(size_t)(dbase + 0) * NN + i] = f2b(o.x);
            ep[(size_t)(dbase + 1) * NN + i] = f2b(o.y);
            ep[(size_t)(dbase + 2) * NN + i] = f2b(o.z);
            ep[(size_t)(dbase + 3) * NN + i] = f2b(o.w);
        }
    }
}

extern "C" void kernel_launch(void* const* d_in, const int* in_sizes, int n_in,
                              void* d_out, int out_size, void* d_ws, size_t ws_size,
                              hipStream_t stream) {
    const float* emb  = (const float*)d_in[0];
    const float* freq = (const float*)d_in[1];
    const float* rm   = (const float*)d_in[2];
    float* out = (float*)d_out;
    char* ws = (char*)d_ws;

    const size_t eBytes   = (size_t)BB * NN * DD * 4;     // 4 MB
    const size_t eTBytes  = (size_t)BB * DD * NN * 2;     // 2 MB
    const size_t bnBytes  = (size_t)BB * NN * 4;          // 64 KB
    const size_t rmbBytes = (size_t)BB * NN * NN * 2;     // 67 MB
    float* e_f32[2] = { (float*)ws, (float*)(ws + eBytes) };
    unsigned short* eT[2] = { (unsigned short*)(ws + 2*eBytes),
                              (unsigned short*)(ws + 2*eBytes + eTBytes) };
    float* rowsum = (float*)(ws + 2*eBytes + 2*eTBytes);
    int* echo = (int*)(ws + 2*eBytes + 2*eTBytes + bnBytes);
    unsigned short* rmb = (unsigned short*)(ws + 2*eBytes + 2*eTBytes + 2*bnBytes);
    size_t need_cached = 2*eBytes + 2*eTBytes + 2*bnBytes + rmbBytes;

    int cached = (ws_size >= need_cached) ? 1 : 0;

    prep_norm<<<dim3(BB*NN/64), dim3(256), 0, stream>>>(emb, freq, e_f32[0], eT[0], echo);

    if (cached) {
        // layer 0: fused fp32-read + bf16 cast-out + rowsum + MFMA
        layer0_fused<<<dim3(256), dim3(512), 0, stream>>>(
            rm, eT[0], e_f32[0], echo, rmb, rowsum, e_f32[1], eT[1]);
        for (int l = 1; l < 5; l++) {
            float* dst = (l == 4) ? out : e_f32[(l + 1) & 1];
            layer_fused<<<dim3(256), dim3(512), 0, stream>>>(
                rmb, eT[l & 1], e_f32[l & 1], rowsum, echo,
                dst, eT[(l + 1) & 1], l);
        }
    } else {
        cast_rowsum<false><<<dim3(BB*NN/4), dim3(256), 0, stream>>>(rm, nullptr, rowsum);
        for (int l = 0; l < 5; l++) {
            float* dst = (l == 4) ? out : e_f32[(l + 1) & 1];
            layer_step_fb<<<dim3(NN/32, BB), dim3(512), 0, stream>>>(
                rm, eT[l & 1], e_f32[l & 1], rowsum, echo,
                dst, eT[(l + 1) & 1], l);
        }
    }
}